// Round 1
// baseline (1422.371 us; speedup 1.0000x reference)
//
#include <hip/hip_runtime.h>
#include <cstdint>
#include <cstddef>

#define NSAMP 64
#define NPT   16384
#define NLVL  4

// ---------------------------------------------------------------------------
// Kernel 0: fold BatchNorm into weights/bias.
//   y = ((W x + b) - m) * g/sqrt(v+eps) + be  ==  (W*s) x + ((b-m)*s + be)
// ---------------------------------------------------------------------------
__global__ __launch_bounds__(256) void prep_kernel(
    const float* __restrict__ w1, const float* __restrict__ b1, const float* __restrict__ g1,
    const float* __restrict__ be1, const float* __restrict__ m1, const float* __restrict__ v1,
    const float* __restrict__ w2, const float* __restrict__ b2, const float* __restrict__ g2,
    const float* __restrict__ be2, const float* __restrict__ m2, const float* __restrict__ v2,
    const float* __restrict__ w3, const float* __restrict__ b3, const float* __restrict__ g3,
    const float* __restrict__ be3, const float* __restrict__ m3, const float* __restrict__ v3,
    float* __restrict__ w1f, float* __restrict__ fb1,
    float* __restrict__ w2f, float* __restrict__ fb2,
    float* __restrict__ w3f, float* __restrict__ fb3)
{
    const int t  = blockIdx.x * 256 + threadIdx.x;
    const int nt = gridDim.x * 256;
    const float eps = 1e-5f;
    for (int i = t; i < 64 * 3; i += nt)   w1f[i] = w1[i] * (g1[i / 3] / sqrtf(v1[i / 3] + eps));
    for (int i = t; i < 64; i += nt)       fb1[i] = (b1[i] - m1[i]) * (g1[i] / sqrtf(v1[i] + eps)) + be1[i];
    for (int i = t; i < 128 * 64; i += nt) w2f[i] = w2[i] * (g2[i / 64] / sqrtf(v2[i / 64] + eps));
    for (int i = t; i < 128; i += nt)      fb2[i] = (b2[i] - m2[i]) * (g2[i] / sqrtf(v2[i] + eps)) + be2[i];
    for (int i = t; i < 256 * 128; i += nt) w3f[i] = w3[i] * (g3[i / 128] / sqrtf(v3[i / 128] + eps));
    for (int i = t; i < 256; i += nt)      fb3[i] = (b3[i] - m3[i]) * (g3[i] / sqrtf(v3[i] + eps)) + be3[i];
}

// ---------------------------------------------------------------------------
// Kernel 1: grouping. One wave per (b,s). Nested masks: level 0 (hmax=0.01)
// is the most restrictive, so once cnt0 >= 64 all levels are full.
// top_k(-key) == first 64 passing indices in ascending order, which a
// ballot + prefix-popcount scan reproduces exactly. Padding slots get the
// slot-0 value (first valid point), or d_rot of point 0 if no valid point.
// Output gx layout: [g=(b*1024+s)][lvl][chan(h,u,v)][sample] .
// ---------------------------------------------------------------------------
__global__ __launch_bounds__(256) void group_kernel(
    const float* __restrict__ seed, const float* __restrict__ pc,
    const float* __restrict__ rot, float* __restrict__ gx)
{
    const int wave = threadIdx.x >> 6;
    const int lane = threadIdx.x & 63;
    const int g = blockIdx.x * 4 + wave;   // 0..2047
    const int b = g >> 10;
    const int s = g & 1023;

    const float* sd = seed + (size_t)(b * 1024 + s) * 3;
    const float sx = sd[0], sy = sd[1], sz = sd[2];
    const float* R = rot + (size_t)(b * 1024 + s) * 9;
    const float r00 = R[0], r01 = R[1], r02 = R[2];
    const float r10 = R[3], r11 = R[4], r12 = R[5];
    const float r20 = R[6], r21 = R[7], r22 = R[8];

    const float* pcb = pc + (size_t)b * NPT * 3;
    float* outg = gx + (size_t)g * (NLVL * 3 * NSAMP);

    __shared__ float firstv[4][NLVL][3];

    int cnt0 = 0, cnt1 = 0, cnt2 = 0, cnt3 = 0;
    const unsigned long long lanemask = (1ull << lane) - 1ull;

    for (int it = 0; it < NPT / 64; ++it) {
        const int n = it * 64 + lane;
        const float px = pcb[n * 3 + 0], py = pcb[n * 3 + 1], pz = pcb[n * 3 + 2];
        const float dx = px - sx, dy = py - sy, dz = pz - sz;
        const float h = dx * r00 + dy * r10 + dz * r20;
        const float u = dx * r01 + dy * r11 + dz * r21;
        const float v = dx * r02 + dy * r12 + dz * r22;
        const float r2 = u * u + v * v;
        const bool base = (r2 < 0.0025f) && (h > -0.02f);

        #pragma unroll
        for (int l = 0; l < NLVL; ++l) {
            const float hm = (l == 0) ? 0.01f : (l == 1) ? 0.02f : (l == 2) ? 0.03f : 0.04f;
            const bool m = base && (h < hm);
            const unsigned long long bal = __ballot(m);
            int& cnt = (l == 0) ? cnt0 : (l == 1) ? cnt1 : (l == 2) ? cnt2 : cnt3;
            const int pos = cnt + (int)__popcll(bal & lanemask);
            if (m && pos < NSAMP) {
                float* o = outg + l * 3 * NSAMP;
                o[pos] = h;
                o[NSAMP + pos] = u;
                o[2 * NSAMP + pos] = v;
                if (pos == 0) {
                    firstv[wave][l][0] = h;
                    firstv[wave][l][1] = u;
                    firstv[wave][l][2] = v;
                }
            }
            cnt += (int)__popcll(bal);
        }
        if (cnt0 >= NSAMP) break;   // wave-uniform: level 0 fills last
    }

    __syncthreads();   // make firstv (LDS) visible

    #pragma unroll
    for (int l = 0; l < NLVL; ++l) {
        const int cnt = (l == 0) ? cnt0 : (l == 1) ? cnt1 : (l == 2) ? cnt2 : cnt3;
        const int c = cnt < NSAMP ? cnt : NSAMP;
        float f0, f1, f2;
        if (c == 0) {
            // no valid point: fall back to d_rot of point index 0
            const float dx = pcb[0] - sx, dy = pcb[1] - sy, dz = pcb[2] - sz;
            f0 = dx * r00 + dy * r10 + dz * r20;
            f1 = dx * r01 + dy * r11 + dz * r21;
            f2 = dx * r02 + dy * r12 + dz * r22;
        } else {
            f0 = firstv[wave][l][0];
            f1 = firstv[wave][l][1];
            f2 = firstv[wave][l][2];
        }
        if (lane >= c) {
            float* o = outg + l * 3 * NSAMP;
            o[lane] = f0;
            o[NSAMP + lane] = f1;
            o[2 * NSAMP + lane] = f2;
        }
    }
}

// ---------------------------------------------------------------------------
// Kernel 2: fused 3-layer MLP + max-pool. One block (256 thr = 4 waves) per
// group gp=(b,s,lvl). Lane = sample n; each wave covers output channels
// o = wave + 4k (wave-uniform -> scalar weight loads via readfirstlane).
// h1 (64x64) and h2 (128x64) live in LDS; 64-float rows -> 2 lanes/bank
// (free on CDNA4). One ds_read amortized over 8 FMAs keeps this VALU-bound.
// Final max over the 64 samples = shfl_xor butterfly across the wave.
// ---------------------------------------------------------------------------
__global__ __launch_bounds__(256) void mlp_kernel(
    const float* __restrict__ gx,
    const float* __restrict__ w1f, const float* __restrict__ fb1,
    const float* __restrict__ w2f, const float* __restrict__ fb2,
    const float* __restrict__ w3f, const float* __restrict__ fb3,
    float* __restrict__ out)
{
    __shared__ float h1[64][64];
    __shared__ float h2[128][64];

    const int gp  = blockIdx.x;          // 0..8191
    const int b   = gp >> 12;
    const int s   = (gp >> 2) & 1023;
    const int lvl = gp & 3;
    const int n   = threadIdx.x & 63;    // sample
    const int w   = threadIdx.x >> 6;    // wave

    const float* xb = gx + (size_t)gp * 192;
    const float x0 = xb[n], x1 = xb[64 + n], x2 = xb[128 + n];

    // Layer 1: 3 -> 64
    #pragma unroll
    for (int k = 0; k < 16; ++k) {
        const int o = __builtin_amdgcn_readfirstlane(w + 4 * k);
        const float a = fb1[o] + w1f[o * 3] * x0 + w1f[o * 3 + 1] * x1 + w1f[o * 3 + 2] * x2;
        h1[w + 4 * k][n] = fmaxf(a, 0.f);
    }
    __syncthreads();

    // Layer 2: 64 -> 128
    for (int kc = 0; kc < 4; ++kc) {
        float acc[8];
        int oo[8];
        #pragma unroll
        for (int j = 0; j < 8; ++j) {
            oo[j] = __builtin_amdgcn_readfirstlane(w + 4 * (8 * kc + j));
            acc[j] = fb2[oo[j]];
        }
        #pragma unroll 4
        for (int c = 0; c < 64; ++c) {
            const float hc = h1[c][n];
            #pragma unroll
            for (int j = 0; j < 8; ++j) acc[j] += w2f[oo[j] * 64 + c] * hc;
        }
        #pragma unroll
        for (int j = 0; j < 8; ++j) h2[w + 4 * (8 * kc + j)][n] = fmaxf(acc[j], 0.f);
    }
    __syncthreads();

    // Layer 3: 128 -> 256, fused ReLU + max over samples
    for (int kc = 0; kc < 8; ++kc) {
        float acc[8];
        int oo[8];
        #pragma unroll
        for (int j = 0; j < 8; ++j) {
            oo[j] = __builtin_amdgcn_readfirstlane(w + 4 * (8 * kc + j));
            acc[j] = fb3[oo[j]];
        }
        #pragma unroll 4
        for (int c = 0; c < 128; ++c) {
            const float hc = h2[c][n];
            #pragma unroll
            for (int j = 0; j < 8; ++j) acc[j] += w3f[oo[j] * 128 + c] * hc;
        }
        #pragma unroll
        for (int j = 0; j < 8; ++j) {
            float y = fmaxf(acc[j], 0.f);
            #pragma unroll
            for (int off = 32; off >= 1; off >>= 1) y = fmaxf(y, __shfl_xor(y, off));
            if (n == 0) {
                const int o = w + 4 * (8 * kc + j);
                out[(((size_t)b * 256 + o) * 1024 + s) * 4 + lvl] = y;
            }
        }
    }
}

// ---------------------------------------------------------------------------
// Workspace layout (floats):
//   gx : 2048 * 4 * 3 * 64 = 1,572,864
//   w1f: 192   fb1: 64
//   w2f: 8192  fb2: 128
//   w3f: 32768 fb3: 256
// total ~6.3 MB
// ---------------------------------------------------------------------------
extern "C" void kernel_launch(void* const* d_in, const int* in_sizes, int n_in,
                              void* d_out, int out_size, void* d_ws, size_t ws_size,
                              hipStream_t stream) {
    const float* seed = (const float*)d_in[0];
    const float* pc   = (const float*)d_in[1];
    const float* rot  = (const float*)d_in[2];
    const float* w1 = (const float*)d_in[3];
    const float* b1 = (const float*)d_in[4];
    const float* g1 = (const float*)d_in[5];
    const float* be1 = (const float*)d_in[6];
    const float* m1 = (const float*)d_in[7];
    const float* v1 = (const float*)d_in[8];
    const float* w2 = (const float*)d_in[9];
    const float* b2 = (const float*)d_in[10];
    const float* g2 = (const float*)d_in[11];
    const float* be2 = (const float*)d_in[12];
    const float* m2 = (const float*)d_in[13];
    const float* v2 = (const float*)d_in[14];
    const float* w3 = (const float*)d_in[15];
    const float* b3 = (const float*)d_in[16];
    const float* g3 = (const float*)d_in[17];
    const float* be3 = (const float*)d_in[18];
    const float* m3 = (const float*)d_in[19];
    const float* v3 = (const float*)d_in[20];

    float* ws  = (float*)d_ws;
    float* gx  = ws;
    float* w1f = ws + 1572864;
    float* fb1 = w1f + 192;
    float* w2f = fb1 + 64;
    float* fb2 = w2f + 8192;
    float* w3f = fb2 + 128;
    float* fb3 = w3f + 32768;

    prep_kernel<<<64, 256, 0, stream>>>(w1, b1, g1, be1, m1, v1,
                                        w2, b2, g2, be2, m2, v2,
                                        w3, b3, g3, be3, m3, v3,
                                        w1f, fb1, w2f, fb2, w3f, fb3);
    group_kernel<<<512, 256, 0, stream>>>(seed, pc, rot, gx);
    mlp_kernel<<<8192, 256, 0, stream>>>(gx, w1f, fb1, w2f, fb2, w3f, fb3,
                                         (float*)d_out);
}

// Round 2
// 356.844 us; speedup vs baseline: 3.9860x; 3.9860x over previous
//
#include <hip/hip_runtime.h>
#include <cstdint>
#include <cstddef>

#define NSAMP 64
#define NPT   16384
#define NLVL  4

typedef __attribute__((ext_vector_type(8))) short  short8;
typedef __attribute__((ext_vector_type(4))) float  floatx4;
typedef __attribute__((ext_vector_type(4))) unsigned int uintx4;
typedef __attribute__((ext_vector_type(2))) unsigned int uintx2;

// fp32 -> bf16 round-to-nearest-even (values are finite; no NaN handling needed)
__device__ __forceinline__ unsigned short f2bf(float x) {
    union { float f; unsigned int u; } c; c.f = x;
    unsigned int r = (c.u + 0x7fffu + ((c.u >> 16) & 1u)) >> 16;
    return (unsigned short)r;
}

// ---------------------------------------------------------------------------
// Kernel 0: fold BatchNorm into weights/bias; W2/W3 emitted as bf16.
//   y = ((W x + b) - m) * g/sqrt(v+eps) + be  ==  (W*s) x + ((b-m)*s + be)
// ---------------------------------------------------------------------------
__global__ __launch_bounds__(256) void prep_kernel(
    const float* __restrict__ w1, const float* __restrict__ b1, const float* __restrict__ g1,
    const float* __restrict__ be1, const float* __restrict__ m1, const float* __restrict__ v1,
    const float* __restrict__ w2, const float* __restrict__ b2, const float* __restrict__ g2,
    const float* __restrict__ be2, const float* __restrict__ m2, const float* __restrict__ v2,
    const float* __restrict__ w3, const float* __restrict__ b3, const float* __restrict__ g3,
    const float* __restrict__ be3, const float* __restrict__ m3, const float* __restrict__ v3,
    float* __restrict__ w1f, float* __restrict__ fb1,
    unsigned short* __restrict__ w2b, float* __restrict__ fb2,
    unsigned short* __restrict__ w3b, float* __restrict__ fb3)
{
    const int t  = blockIdx.x * 256 + threadIdx.x;
    const int nt = gridDim.x * 256;
    const float eps = 1e-5f;
    for (int i = t; i < 64 * 3; i += nt)    w1f[i] = w1[i] * (g1[i / 3] / sqrtf(v1[i / 3] + eps));
    for (int i = t; i < 64; i += nt)        fb1[i] = (b1[i] - m1[i]) * (g1[i] / sqrtf(v1[i] + eps)) + be1[i];
    for (int i = t; i < 128 * 64; i += nt)  w2b[i] = f2bf(w2[i] * (g2[i / 64] / sqrtf(v2[i / 64] + eps)));
    for (int i = t; i < 128; i += nt)       fb2[i] = (b2[i] - m2[i]) * (g2[i] / sqrtf(v2[i] + eps)) + be2[i];
    for (int i = t; i < 256 * 128; i += nt) w3b[i] = f2bf(w3[i] * (g3[i / 128] / sqrtf(v3[i / 128] + eps)));
    for (int i = t; i < 256; i += nt)       fb3[i] = (b3[i] - m3[i]) * (g3[i] / sqrtf(v3[i] + eps)) + be3[i];
}

// ---------------------------------------------------------------------------
// Kernel 1: grouping (unchanged from round 0 — passed, ~150us; revisit later).
// One wave per (b,s); ballot + prefix-popcount reproduces top_k(-key) exactly.
// Output gx layout: [g=(b*1024+s)][lvl][chan(h,u,v)][sample].
// ---------------------------------------------------------------------------
__global__ __launch_bounds__(256) void group_kernel(
    const float* __restrict__ seed, const float* __restrict__ pc,
    const float* __restrict__ rot, float* __restrict__ gx)
{
    const int wave = threadIdx.x >> 6;
    const int lane = threadIdx.x & 63;
    const int g = blockIdx.x * 4 + wave;   // 0..2047
    const int b = g >> 10;
    const int s = g & 1023;

    const float* sd = seed + (size_t)(b * 1024 + s) * 3;
    const float sx = sd[0], sy = sd[1], sz = sd[2];
    const float* R = rot + (size_t)(b * 1024 + s) * 9;
    const float r00 = R[0], r01 = R[1], r02 = R[2];
    const float r10 = R[3], r11 = R[4], r12 = R[5];
    const float r20 = R[6], r21 = R[7], r22 = R[8];

    const float* pcb = pc + (size_t)b * NPT * 3;
    float* outg = gx + (size_t)g * (NLVL * 3 * NSAMP);

    __shared__ float firstv[4][NLVL][3];

    int cnt0 = 0, cnt1 = 0, cnt2 = 0, cnt3 = 0;
    const unsigned long long lanemask = (1ull << lane) - 1ull;

    for (int it = 0; it < NPT / 64; ++it) {
        const int n = it * 64 + lane;
        const float px = pcb[n * 3 + 0], py = pcb[n * 3 + 1], pz = pcb[n * 3 + 2];
        const float dx = px - sx, dy = py - sy, dz = pz - sz;
        const float h = dx * r00 + dy * r10 + dz * r20;
        const float u = dx * r01 + dy * r11 + dz * r21;
        const float v = dx * r02 + dy * r12 + dz * r22;
        const float r2 = u * u + v * v;
        const bool base = (r2 < 0.0025f) && (h > -0.02f);

        #pragma unroll
        for (int l = 0; l < NLVL; ++l) {
            const float hm = (l == 0) ? 0.01f : (l == 1) ? 0.02f : (l == 2) ? 0.03f : 0.04f;
            const bool m = base && (h < hm);
            const unsigned long long bal = __ballot(m);
            int& cnt = (l == 0) ? cnt0 : (l == 1) ? cnt1 : (l == 2) ? cnt2 : cnt3;
            const int pos = cnt + (int)__popcll(bal & lanemask);
            if (m && pos < NSAMP) {
                float* o = outg + l * 3 * NSAMP;
                o[pos] = h;
                o[NSAMP + pos] = u;
                o[2 * NSAMP + pos] = v;
                if (pos == 0) {
                    firstv[wave][l][0] = h;
                    firstv[wave][l][1] = u;
                    firstv[wave][l][2] = v;
                }
            }
            cnt += (int)__popcll(bal);
        }
        if (cnt0 >= NSAMP) break;   // wave-uniform: level 0 fills last
    }

    __syncthreads();   // make firstv (LDS) visible

    #pragma unroll
    for (int l = 0; l < NLVL; ++l) {
        const int cnt = (l == 0) ? cnt0 : (l == 1) ? cnt1 : (l == 2) ? cnt2 : cnt3;
        const int c = cnt < NSAMP ? cnt : NSAMP;
        float f0, f1, f2;
        if (c == 0) {
            const float dx = pcb[0] - sx, dy = pcb[1] - sy, dz = pcb[2] - sz;
            f0 = dx * r00 + dy * r10 + dz * r20;
            f1 = dx * r01 + dy * r11 + dz * r21;
            f2 = dx * r02 + dy * r12 + dz * r22;
        } else {
            f0 = firstv[wave][l][0];
            f1 = firstv[wave][l][1];
            f2 = firstv[wave][l][2];
        }
        if (lane >= c) {
            float* o = outg + l * 3 * NSAMP;
            o[lane] = f0;
            o[NSAMP + lane] = f1;
            o[2 * NSAMP + lane] = f2;
        }
    }
}

// ---------------------------------------------------------------------------
// Kernel 2: MFMA MLP. One block (4 waves) per group gp=(b,s,lvl).
//
// GEMM mapping (D = A*B, mfma_f32_16x16x32_bf16):
//   A = W (out-ch x in-ch, row-major bf16 from global/L2; same for all blocks)
//     lane reads A[m0+(lane&15)][k0+quad*8+j] -> 16B contiguous
//   B = H^T in LDS: ht[n][k] (k contiguous, row padded +8 bf16 -> 2-way bank
//     aliasing only, free on CDNA4)
//     lane reads ht[n0+(lane&15)][k0+quad*8+j] -> ds_read_b128
//   D: row m = m0+quad*4+reg, col n = n0+(lane&15)  (m89-verified layout)
//
// Layer1 (K=3) on VALU, writes h1t directly in B layout. Layer2: M=128,K=64.
// Layer3: M=256,K=128, epilogue fuses bias+relu+max-over-samples (exact:
// bias is per-channel so relu(max_n acc + b) == max_n relu(acc+b)).
// ---------------------------------------------------------------------------
__global__ __launch_bounds__(256) void mlp_kernel(
    const float* __restrict__ gx,
    const float* __restrict__ w1f, const float* __restrict__ fb1,
    const unsigned short* __restrict__ w2b, const float* __restrict__ fb2,
    const unsigned short* __restrict__ w3b, const float* __restrict__ fb3,
    float* __restrict__ out)
{
    __shared__ unsigned short h1t[64 * 72];    //  9216 B, stride 72 bf16
    __shared__ unsigned short h2t[64 * 136];   // 17408 B, stride 136 bf16

    const int gp  = blockIdx.x;          // 0..8191
    const int b   = gp >> 12;
    const int s   = (gp >> 2) & 1023;
    const int lvl = gp & 3;
    const int tid = threadIdx.x;
    const int n      = tid & 63;         // sample lane
    const int w      = tid >> 6;         // wave
    const int lane15 = tid & 15;
    const int quad   = (tid & 63) >> 4;

    // ---- Layer 1: 3 -> 64 (VALU fp32), write h1t[n][o] in bf16
    {
        const float* xb = gx + (size_t)gp * 192;
        const float x0 = xb[n], x1 = xb[64 + n], x2 = xb[128 + n];
        unsigned int p[8];
        #pragma unroll
        for (int j = 0; j < 8; ++j) {
            const int o0 = w * 16 + 2 * j;
            const float a0 = fb1[o0]     + w1f[o0*3]*x0   + w1f[o0*3+1]*x1 + w1f[o0*3+2]*x2;
            const float a1 = fb1[o0 + 1] + w1f[o0*3+3]*x0 + w1f[o0*3+4]*x1 + w1f[o0*3+5]*x2;
            p[j] = (unsigned int)f2bf(fmaxf(a0, 0.f)) |
                   ((unsigned int)f2bf(fmaxf(a1, 0.f)) << 16);
        }
        uintx4* dst = (uintx4*)&h1t[n * 72 + w * 16];
        dst[0] = (uintx4){p[0], p[1], p[2], p[3]};
        dst[1] = (uintx4){p[4], p[5], p[6], p[7]};
    }
    __syncthreads();

    // ---- Layer 2: 64 -> 128, write h2t in B layout
    {
        short8 bf[4][2];
        #pragma unroll
        for (int nt = 0; nt < 4; ++nt)
            #pragma unroll
            for (int k0 = 0; k0 < 2; ++k0)
                bf[nt][k0] = *(const short8*)&h1t[(nt * 16 + lane15) * 72 + k0 * 32 + quad * 8];

        #pragma unroll
        for (int mi = 0; mi < 2; ++mi) {
            const int m0 = (w * 2 + mi) * 16;
            const short8 a0 = *(const short8*)&w2b[(m0 + lane15) * 64 + quad * 8];
            const short8 a1 = *(const short8*)&w2b[(m0 + lane15) * 64 + 32 + quad * 8];
            const floatx4 bias = *(const floatx4*)&fb2[m0 + quad * 4];
            #pragma unroll
            for (int nt = 0; nt < 4; ++nt) {
                floatx4 acc = bias;
                acc = __builtin_amdgcn_mfma_f32_16x16x32_bf16(a0, bf[nt][0], acc, 0, 0, 0);
                acc = __builtin_amdgcn_mfma_f32_16x16x32_bf16(a1, bf[nt][1], acc, 0, 0, 0);
                const unsigned int q0 = (unsigned int)f2bf(fmaxf(acc[0], 0.f)) |
                                        ((unsigned int)f2bf(fmaxf(acc[1], 0.f)) << 16);
                const unsigned int q1 = (unsigned int)f2bf(fmaxf(acc[2], 0.f)) |
                                        ((unsigned int)f2bf(fmaxf(acc[3], 0.f)) << 16);
                *(uintx2*)&h2t[(nt * 16 + lane15) * 136 + m0 + quad * 4] = (uintx2){q0, q1};
            }
        }
    }
    __syncthreads();

    // ---- Layer 3: 128 -> 256 + fused bias/relu/max-pool over 64 samples
    {
        short8 bf[4][4];
        #pragma unroll
        for (int nt = 0; nt < 4; ++nt)
            #pragma unroll
            for (int k0 = 0; k0 < 4; ++k0)
                bf[nt][k0] = *(const short8*)&h2t[(nt * 16 + lane15) * 136 + k0 * 32 + quad * 8];

        #pragma unroll
        for (int mt = 0; mt < 4; ++mt) {
            const int m0 = (w * 4 + mt) * 16;
            short8 a[4];
            #pragma unroll
            for (int k0 = 0; k0 < 4; ++k0)
                a[k0] = *(const short8*)&w3b[(m0 + lane15) * 128 + k0 * 32 + quad * 8];

            floatx4 acc[4];
            #pragma unroll
            for (int nt = 0; nt < 4; ++nt) acc[nt] = (floatx4){0.f, 0.f, 0.f, 0.f};
            #pragma unroll
            for (int k0 = 0; k0 < 4; ++k0)
                #pragma unroll
                for (int nt = 0; nt < 4; ++nt)
                    acc[nt] = __builtin_amdgcn_mfma_f32_16x16x32_bf16(a[k0], bf[nt][k0], acc[nt], 0, 0, 0);

            const floatx4 bias = *(const floatx4*)&fb3[m0 + quad * 4];
            #pragma unroll
            for (int r = 0; r < 4; ++r) {
                float t = fmaxf(fmaxf(acc[0][r], acc[1][r]), fmaxf(acc[2][r], acc[3][r]));
                t = fmaxf(t, __shfl_xor(t, 1));
                t = fmaxf(t, __shfl_xor(t, 2));
                t = fmaxf(t, __shfl_xor(t, 4));
                t = fmaxf(t, __shfl_xor(t, 8));
                if (lane15 == 0) {
                    const int o = m0 + quad * 4 + r;
                    out[(((size_t)b * 256 + o) * 1024 + s) * 4 + lvl] = fmaxf(t + bias[r], 0.f);
                }
            }
        }
    }
}

// ---------------------------------------------------------------------------
// Workspace layout (float units):
//   gx : 1,572,864            (6.29 MB)
//   w1f: 192   fb1: 64   fb2: 128   fb3: 256
//   w2b: 8192 ushort (= 4096 floats)
//   w3b: 32768 ushort (= 16384 floats)
// total ~6.38 MB
// ---------------------------------------------------------------------------
extern "C" void kernel_launch(void* const* d_in, const int* in_sizes, int n_in,
                              void* d_out, int out_size, void* d_ws, size_t ws_size,
                              hipStream_t stream) {
    const float* seed = (const float*)d_in[0];
    const float* pc   = (const float*)d_in[1];
    const float* rot  = (const float*)d_in[2];
    const float* w1 = (const float*)d_in[3];
    const float* b1 = (const float*)d_in[4];
    const float* g1 = (const float*)d_in[5];
    const float* be1 = (const float*)d_in[6];
    const float* m1 = (const float*)d_in[7];
    const float* v1 = (const float*)d_in[8];
    const float* w2 = (const float*)d_in[9];
    const float* b2 = (const float*)d_in[10];
    const float* g2 = (const float*)d_in[11];
    const float* be2 = (const float*)d_in[12];
    const float* m2 = (const float*)d_in[13];
    const float* v2 = (const float*)d_in[14];
    const float* w3 = (const float*)d_in[15];
    const float* b3 = (const float*)d_in[16];
    const float* g3 = (const float*)d_in[17];
    const float* be3 = (const float*)d_in[18];
    const float* m3 = (const float*)d_in[19];
    const float* v3 = (const float*)d_in[20];

    float* ws  = (float*)d_ws;
    float* gx  = ws;
    float* w1f = ws + 1572864;
    float* fb1 = w1f + 192;
    float* fb2 = fb1 + 64;
    float* fb3 = fb2 + 128;
    unsigned short* w2b = (unsigned short*)(fb3 + 256);
    unsigned short* w3b = (unsigned short*)(fb3 + 256 + 4096);

    prep_kernel<<<64, 256, 0, stream>>>(w1, b1, g1, be1, m1, v1,
                                        w2, b2, g2, be2, m2, v2,
                                        w3, b3, g3, be3, m3, v3,
                                        w1f, fb1, w2b, fb2, w3b, fb3);
    group_kernel<<<512, 256, 0, stream>>>(seed, pc, rot, gx);
    mlp_kernel<<<8192, 256, 0, stream>>>(gx, w1f, fb1, w2b, fb2, w3b, fb3,
                                         (float*)d_out);
}

// Round 3
// 263.714 us; speedup vs baseline: 5.3936x; 1.3532x over previous
//
#include <hip/hip_runtime.h>
#include <cstdint>
#include <cstddef>

#define NSAMP  64
#define NPT    16384
#define NLVL   4
#define NCHUNK 8
#define CHSZ   (NPT / NCHUNK)   // 2048 points per chunk

typedef __attribute__((ext_vector_type(8))) short  short8;
typedef __attribute__((ext_vector_type(4))) float  floatx4;
typedef __attribute__((ext_vector_type(4))) unsigned int uintx4;
typedef __attribute__((ext_vector_type(2))) unsigned int uintx2;

// fp32 -> bf16 round-to-nearest-even (values are finite; no NaN handling needed)
__device__ __forceinline__ unsigned short f2bf(float x) {
    union { float f; unsigned int u; } c; c.f = x;
    unsigned int r = (c.u + 0x7fffu + ((c.u >> 16) & 1u)) >> 16;
    return (unsigned short)r;
}

// ---------------------------------------------------------------------------
// Kernel 0: fold BatchNorm into weights/bias; W2/W3 emitted as bf16.
// ---------------------------------------------------------------------------
__global__ __launch_bounds__(256) void prep_kernel(
    const float* __restrict__ w1, const float* __restrict__ b1, const float* __restrict__ g1,
    const float* __restrict__ be1, const float* __restrict__ m1, const float* __restrict__ v1,
    const float* __restrict__ w2, const float* __restrict__ b2, const float* __restrict__ g2,
    const float* __restrict__ be2, const float* __restrict__ m2, const float* __restrict__ v2,
    const float* __restrict__ w3, const float* __restrict__ b3, const float* __restrict__ g3,
    const float* __restrict__ be3, const float* __restrict__ m3, const float* __restrict__ v3,
    float* __restrict__ w1f, float* __restrict__ fb1,
    unsigned short* __restrict__ w2b, float* __restrict__ fb2,
    unsigned short* __restrict__ w3b, float* __restrict__ fb3)
{
    const int t  = blockIdx.x * 256 + threadIdx.x;
    const int nt = gridDim.x * 256;
    const float eps = 1e-5f;
    for (int i = t; i < 64 * 3; i += nt)    w1f[i] = w1[i] * (g1[i / 3] / sqrtf(v1[i / 3] + eps));
    for (int i = t; i < 64; i += nt)        fb1[i] = (b1[i] - m1[i]) * (g1[i] / sqrtf(v1[i] + eps)) + be1[i];
    for (int i = t; i < 128 * 64; i += nt)  w2b[i] = f2bf(w2[i] * (g2[i / 64] / sqrtf(v2[i / 64] + eps)));
    for (int i = t; i < 128; i += nt)       fb2[i] = (b2[i] - m2[i]) * (g2[i] / sqrtf(v2[i] + eps)) + be2[i];
    for (int i = t; i < 256 * 128; i += nt) w3b[i] = f2bf(w3[i] * (g3[i / 128] / sqrtf(v3[i / 128] + eps)));
    for (int i = t; i < 256; i += nt)       fb3[i] = (b3[i] - m3[i]) * (g3[i] / sqrtf(v3[i] + eps)) + be3[i];
}

// ---------------------------------------------------------------------------
// Kernel 1a: chunked scan. One wave per (seed g, chunk c): 2048 points,
// 4 points/lane/iter via 3x float4 loads. Ballot + prefix-popcount gives the
// first <=64 passing indices per level IN ASCENDING ORDER within the chunk
// (point order = (lane,j) lexicographic = ascending global index).
// Stores uint16 point indices to buf[g][lvl][chunk][64] and raw counts.
// Early exit when level 0 (most restrictive; masks are nested) fills.
// ---------------------------------------------------------------------------
__global__ __launch_bounds__(256) void scan_kernel(
    const float* __restrict__ seedp, const float* __restrict__ pc,
    const float* __restrict__ rot, unsigned short* __restrict__ buf,
    int* __restrict__ cnts)
{
    const int lane = threadIdx.x & 63;
    const int W = blockIdx.x * 4 + (threadIdx.x >> 6);   // 0..16383
    const int g = W >> 3;          // seed 0..2047
    const int c = W & 7;           // chunk 0..7
    const int b = g >> 10;

    const float* sd = seedp + (size_t)g * 3;
    const float sx = sd[0], sy = sd[1], sz = sd[2];
    const float* R = rot + (size_t)g * 9;
    const float r00 = R[0], r01 = R[1], r02 = R[2];
    const float r10 = R[3], r11 = R[4], r12 = R[5];
    const float r20 = R[6], r21 = R[7], r22 = R[8];

    const float* pcb = pc + (size_t)b * NPT * 3;
    unsigned short* bufg = buf + (size_t)g * (NLVL * NCHUNK * 64);

    int cnt0 = 0, cnt1 = 0, cnt2 = 0, cnt3 = 0;
    const unsigned long long lm = (1ull << lane) - 1ull;
    const int base = c * CHSZ;

    for (int it = 0; it < CHSZ / 256; ++it) {
        const int p0 = base + it * 256 + lane * 4;
        const float4 q0 = *(const float4*)(pcb + (size_t)p0 * 3);
        const float4 q1 = *(const float4*)(pcb + (size_t)p0 * 3 + 4);
        const float4 q2 = *(const float4*)(pcb + (size_t)p0 * 3 + 8);

        float hh[4];
        bool  bm[4];
        {
            const float px[4] = {q0.x, q0.w, q1.z, q2.y};
            const float py[4] = {q0.y, q1.x, q1.w, q2.z};
            const float pz[4] = {q0.z, q1.y, q2.x, q2.w};
            #pragma unroll
            for (int j = 0; j < 4; ++j) {
                const float dx = px[j] - sx, dy = py[j] - sy, dz = pz[j] - sz;
                const float h = dx * r00 + dy * r10 + dz * r20;
                const float u = dx * r01 + dy * r11 + dz * r21;
                const float v = dx * r02 + dy * r12 + dz * r22;
                const float r2 = u * u + v * v;
                hh[j] = h;
                bm[j] = (r2 < 0.0025f) && (h > -0.02f);
            }
        }

        #pragma unroll
        for (int l = 0; l < NLVL; ++l) {
            const float hm = (l == 0) ? 0.01f : (l == 1) ? 0.02f : (l == 2) ? 0.03f : 0.04f;
            const bool m0 = bm[0] && (hh[0] < hm);
            const bool m1 = bm[1] && (hh[1] < hm);
            const bool m2 = bm[2] && (hh[2] < hm);
            const bool m3 = bm[3] && (hh[3] < hm);
            const unsigned long long b0 = __ballot(m0);
            const unsigned long long b1 = __ballot(m1);
            const unsigned long long b2 = __ballot(m2);
            const unsigned long long b3 = __ballot(m3);
            int& cnt = (l == 0) ? cnt0 : (l == 1) ? cnt1 : (l == 2) ? cnt2 : cnt3;
            const int lanePref = (int)(__popcll(b0 & lm) + __popcll(b1 & lm) +
                                       __popcll(b2 & lm) + __popcll(b3 & lm));
            unsigned short* ob = bufg + (l * NCHUNK + c) * 64;
            int own = 0;
            if (m0) { const int pos = cnt + lanePref;       if (pos < 64) ob[pos] = (unsigned short)(p0);     own = 1; }
            if (m1) { const int pos = cnt + lanePref + own; if (pos < 64) ob[pos] = (unsigned short)(p0 + 1); ++own; }
            if (m2) { const int pos = cnt + lanePref + own; if (pos < 64) ob[pos] = (unsigned short)(p0 + 2); ++own; }
            if (m3) { const int pos = cnt + lanePref + own; if (pos < 64) ob[pos] = (unsigned short)(p0 + 3); ++own; }
            cnt += (int)(__popcll(b0) + __popcll(b1) + __popcll(b2) + __popcll(b3));
        }
        if (cnt0 >= NSAMP) break;   // nested masks: level 0 fills last
    }

    if (lane == 0) {
        int* cg = cnts + (size_t)g * (NLVL * NCHUNK);
        cg[0 * NCHUNK + c] = cnt0;
        cg[1 * NCHUNK + c] = cnt1;
        cg[2 * NCHUNK + c] = cnt2;
        cg[3 * NCHUNK + c] = cnt3;
    }
}

// ---------------------------------------------------------------------------
// Kernel 1b: merge. One wave per (seed, lvl). Concatenate per-chunk ordered
// selections (each capped at 64 — more than 64 from one chunk can never be
// needed), take first 64, pad with the overall-first hit (or point 0 if no
// hit). Recompute (h,u,v) by rotation and write gx in MLP layout.
// ---------------------------------------------------------------------------
__global__ __launch_bounds__(256) void merge_kernel(
    const float* __restrict__ seedp, const float* __restrict__ pc,
    const float* __restrict__ rot, const unsigned short* __restrict__ buf,
    const int* __restrict__ cnts, float* __restrict__ gx)
{
    const int lane = threadIdx.x & 63;
    const int W = blockIdx.x * 4 + (threadIdx.x >> 6);   // 0..8191
    const int g = W >> 2;
    const int l = W & 3;
    const int b = g >> 10;

    const int* cg = cnts + (size_t)g * (NLVL * NCHUNK) + l * NCHUNK;
    const unsigned short* bl = buf + (size_t)g * (NLVL * NCHUNK * 64) + l * (NCHUNK * 64);

    int idx = -1, acc = 0, firstIdx = -1;
    #pragma unroll
    for (int c = 0; c < NCHUNK; ++c) {
        const int cn = min(cg[c], 64);
        if (cn > 0 && firstIdx < 0) firstIdx = (int)bl[c * 64];
        if (lane >= acc && lane < acc + cn) idx = (int)bl[c * 64 + (lane - acc)];
        acc += cn;
    }
    if (idx < 0) idx = (firstIdx >= 0) ? firstIdx : 0;

    const float* sd = seedp + (size_t)g * 3;
    const float sx = sd[0], sy = sd[1], sz = sd[2];
    const float* R = rot + (size_t)g * 9;
    const float* pp = pc + ((size_t)b * NPT + idx) * 3;
    const float dx = pp[0] - sx, dy = pp[1] - sy, dz = pp[2] - sz;
    const float h = dx * R[0] + dy * R[3] + dz * R[6];
    const float u = dx * R[1] + dy * R[4] + dz * R[7];
    const float v = dx * R[2] + dy * R[5] + dz * R[8];

    float* o = gx + ((size_t)g * 4 + l) * 192;
    o[lane]       = h;
    o[64 + lane]  = u;
    o[128 + lane] = v;
}

// ---------------------------------------------------------------------------
// Kernel 2: MFMA MLP (unchanged from round 1).
// ---------------------------------------------------------------------------
__global__ __launch_bounds__(256) void mlp_kernel(
    const float* __restrict__ gx,
    const float* __restrict__ w1f, const float* __restrict__ fb1,
    const unsigned short* __restrict__ w2b, const float* __restrict__ fb2,
    const unsigned short* __restrict__ w3b, const float* __restrict__ fb3,
    float* __restrict__ out)
{
    __shared__ unsigned short h1t[64 * 72];    //  9216 B, stride 72 bf16
    __shared__ unsigned short h2t[64 * 136];   // 17408 B, stride 136 bf16

    const int gp  = blockIdx.x;          // 0..8191
    const int b   = gp >> 12;
    const int s   = (gp >> 2) & 1023;
    const int lvl = gp & 3;
    const int tid = threadIdx.x;
    const int n      = tid & 63;         // sample lane
    const int w      = tid >> 6;         // wave
    const int lane15 = tid & 15;
    const int quad   = (tid & 63) >> 4;

    // ---- Layer 1: 3 -> 64 (VALU fp32), write h1t[n][o] in bf16
    {
        const float* xb = gx + (size_t)gp * 192;
        const float x0 = xb[n], x1 = xb[64 + n], x2 = xb[128 + n];
        unsigned int p[8];
        #pragma unroll
        for (int j = 0; j < 8; ++j) {
            const int o0 = w * 16 + 2 * j;
            const float a0 = fb1[o0]     + w1f[o0*3]*x0   + w1f[o0*3+1]*x1 + w1f[o0*3+2]*x2;
            const float a1 = fb1[o0 + 1] + w1f[o0*3+3]*x0 + w1f[o0*3+4]*x1 + w1f[o0*3+5]*x2;
            p[j] = (unsigned int)f2bf(fmaxf(a0, 0.f)) |
                   ((unsigned int)f2bf(fmaxf(a1, 0.f)) << 16);
        }
        uintx4* dst = (uintx4*)&h1t[n * 72 + w * 16];
        dst[0] = (uintx4){p[0], p[1], p[2], p[3]};
        dst[1] = (uintx4){p[4], p[5], p[6], p[7]};
    }
    __syncthreads();

    // ---- Layer 2: 64 -> 128, write h2t in B layout
    {
        short8 bf[4][2];
        #pragma unroll
        for (int nt = 0; nt < 4; ++nt)
            #pragma unroll
            for (int k0 = 0; k0 < 2; ++k0)
                bf[nt][k0] = *(const short8*)&h1t[(nt * 16 + lane15) * 72 + k0 * 32 + quad * 8];

        #pragma unroll
        for (int mi = 0; mi < 2; ++mi) {
            const int m0 = (w * 2 + mi) * 16;
            const short8 a0 = *(const short8*)&w2b[(m0 + lane15) * 64 + quad * 8];
            const short8 a1 = *(const short8*)&w2b[(m0 + lane15) * 64 + 32 + quad * 8];
            const floatx4 bias = *(const floatx4*)&fb2[m0 + quad * 4];
            #pragma unroll
            for (int nt = 0; nt < 4; ++nt) {
                floatx4 acc = bias;
                acc = __builtin_amdgcn_mfma_f32_16x16x32_bf16(a0, bf[nt][0], acc, 0, 0, 0);
                acc = __builtin_amdgcn_mfma_f32_16x16x32_bf16(a1, bf[nt][1], acc, 0, 0, 0);
                const unsigned int q0 = (unsigned int)f2bf(fmaxf(acc[0], 0.f)) |
                                        ((unsigned int)f2bf(fmaxf(acc[1], 0.f)) << 16);
                const unsigned int q1 = (unsigned int)f2bf(fmaxf(acc[2], 0.f)) |
                                        ((unsigned int)f2bf(fmaxf(acc[3], 0.f)) << 16);
                *(uintx2*)&h2t[(nt * 16 + lane15) * 136 + m0 + quad * 4] = (uintx2){q0, q1};
            }
        }
    }
    __syncthreads();

    // ---- Layer 3: 128 -> 256 + fused bias/relu/max-pool over 64 samples
    {
        short8 bf[4][4];
        #pragma unroll
        for (int nt = 0; nt < 4; ++nt)
            #pragma unroll
            for (int k0 = 0; k0 < 4; ++k0)
                bf[nt][k0] = *(const short8*)&h2t[(nt * 16 + lane15) * 136 + k0 * 32 + quad * 8];

        #pragma unroll
        for (int mt = 0; mt < 4; ++mt) {
            const int m0 = (w * 4 + mt) * 16;
            short8 a[4];
            #pragma unroll
            for (int k0 = 0; k0 < 4; ++k0)
                a[k0] = *(const short8*)&w3b[(m0 + lane15) * 128 + k0 * 32 + quad * 8];

            floatx4 acc[4];
            #pragma unroll
            for (int nt = 0; nt < 4; ++nt) acc[nt] = (floatx4){0.f, 0.f, 0.f, 0.f};
            #pragma unroll
            for (int k0 = 0; k0 < 4; ++k0)
                #pragma unroll
                for (int nt = 0; nt < 4; ++nt)
                    acc[nt] = __builtin_amdgcn_mfma_f32_16x16x32_bf16(a[k0], bf[nt][k0], acc[nt], 0, 0, 0);

            const floatx4 bias = *(const floatx4*)&fb3[m0 + quad * 4];
            #pragma unroll
            for (int r = 0; r < 4; ++r) {
                float t = fmaxf(fmaxf(acc[0][r], acc[1][r]), fmaxf(acc[2][r], acc[3][r]));
                t = fmaxf(t, __shfl_xor(t, 1));
                t = fmaxf(t, __shfl_xor(t, 2));
                t = fmaxf(t, __shfl_xor(t, 4));
                t = fmaxf(t, __shfl_xor(t, 8));
                if (lane15 == 0) {
                    const int o = m0 + quad * 4 + r;
                    out[(((size_t)b * 256 + o) * 1024 + s) * 4 + lvl] = fmaxf(t + bias[r], 0.f);
                }
            }
        }
    }
}

// ---------------------------------------------------------------------------
// Workspace layout (float units):
//   gx : 1,572,864
//   w1f: 192  fb1: 64  fb2: 128  fb3: 256
//   w2b: 8192 ushort (4096 fl)   w3b: 32768 ushort (16384 fl)
//   buf: 2048*4*8*64 ushort = 4,194,304 ushort (2,097,152 fl)
//   cnts: 2048*4*8 int = 65,536 int
// total ~15.1 MB
// ---------------------------------------------------------------------------
extern "C" void kernel_launch(void* const* d_in, const int* in_sizes, int n_in,
                              void* d_out, int out_size, void* d_ws, size_t ws_size,
                              hipStream_t stream) {
    const float* seed = (const float*)d_in[0];
    const float* pc   = (const float*)d_in[1];
    const float* rot  = (const float*)d_in[2];
    const float* w1 = (const float*)d_in[3];
    const float* b1 = (const float*)d_in[4];
    const float* g1 = (const float*)d_in[5];
    const float* be1 = (const float*)d_in[6];
    const float* m1 = (const float*)d_in[7];
    const float* v1 = (const float*)d_in[8];
    const float* w2 = (const float*)d_in[9];
    const float* b2 = (const float*)d_in[10];
    const float* g2 = (const float*)d_in[11];
    const float* be2 = (const float*)d_in[12];
    const float* m2 = (const float*)d_in[13];
    const float* v2 = (const float*)d_in[14];
    const float* w3 = (const float*)d_in[15];
    const float* b3 = (const float*)d_in[16];
    const float* g3 = (const float*)d_in[17];
    const float* be3 = (const float*)d_in[18];
    const float* m3 = (const float*)d_in[19];
    const float* v3 = (const float*)d_in[20];

    float* ws  = (float*)d_ws;
    float* gx  = ws;
    float* w1f = ws + 1572864;
    float* fb1 = w1f + 192;
    float* fb2 = fb1 + 64;
    float* fb3 = fb2 + 128;
    unsigned short* w2b = (unsigned short*)(fb3 + 256);
    unsigned short* w3b = (unsigned short*)(fb3 + 256 + 4096);
    unsigned short* buf = (unsigned short*)(fb3 + 256 + 4096 + 16384);
    int* cnts = (int*)(fb3 + 256 + 4096 + 16384 + 2097152);

    prep_kernel<<<64, 256, 0, stream>>>(w1, b1, g1, be1, m1, v1,
                                        w2, b2, g2, be2, m2, v2,
                                        w3, b3, g3, be3, m3, v3,
                                        w1f, fb1, w2b, fb2, w3b, fb3);
    scan_kernel<<<4096, 256, 0, stream>>>(seed, pc, rot, buf, cnts);
    merge_kernel<<<2048, 256, 0, stream>>>(seed, pc, rot, buf, cnts, gx);
    mlp_kernel<<<8192, 256, 0, stream>>>(gx, w1f, fb1, w2b, fb2, w3b, fb3,
                                         (float*)d_out);
}

// Round 5
// 228.458 us; speedup vs baseline: 6.2260x; 1.1543x over previous
//
#include <hip/hip_runtime.h>
#include <hip/hip_bf16.h>
#include <cstdint>
#include <cstddef>

#define NSAMP  64
#define NPT    16384
#define NLVL   4
#define NCHUNK 8
#define CHSZ   (NPT / NCHUNK)   // 2048 points per chunk

typedef __attribute__((ext_vector_type(8))) short  short8;
typedef __attribute__((ext_vector_type(4))) float  floatx4;
typedef __attribute__((ext_vector_type(4))) unsigned int uintx4;
typedef __attribute__((ext_vector_type(2))) unsigned int uintx2;

// fp32 -> bf16 RNE (finite values only)
__device__ __forceinline__ unsigned short f2bf(float x) {
    union { float f; unsigned int u; } c; c.f = x;
    unsigned int r = (c.u + 0x7fffu + ((c.u >> 16) & 1u)) >> 16;
    return (unsigned short)r;
}
__device__ __forceinline__ unsigned int f2bf2(float a, float b) {
    __hip_bfloat162 t = __float22bfloat162_rn(make_float2(a, b));
    union { __hip_bfloat162 h; unsigned int u; } c; c.h = t;
    return c.u;
}
// max over the 16-lane row via DPP row_ror 1/2/4/8 (VALU pipe, no LDS traffic)
__device__ __forceinline__ float fmax_rot16(float v) {
    union { float f; int i; } a, b;
    a.f = v; b.i = __builtin_amdgcn_mov_dpp(a.i, 0x121, 0xf, 0xf, 1); v = fmaxf(v, b.f);
    a.f = v; b.i = __builtin_amdgcn_mov_dpp(a.i, 0x122, 0xf, 0xf, 1); v = fmaxf(v, b.f);
    a.f = v; b.i = __builtin_amdgcn_mov_dpp(a.i, 0x124, 0xf, 0xf, 1); v = fmaxf(v, b.f);
    a.f = v; b.i = __builtin_amdgcn_mov_dpp(a.i, 0x128, 0xf, 0xf, 1); v = fmaxf(v, b.f);
    return v;
}

// ---------------------------------------------------------------------------
// Kernel 0: fold BatchNorm into weights/bias.
// Layer 1 stays FP32 (accuracy: bf16 layer-1 inputs cost 13x absmax, round 4).
// W2/W3 bf16; fb2/fb3 fp32.
// ---------------------------------------------------------------------------
__global__ __launch_bounds__(256) void prep_kernel(
    const float* __restrict__ w1, const float* __restrict__ b1, const float* __restrict__ g1,
    const float* __restrict__ be1, const float* __restrict__ m1, const float* __restrict__ v1,
    const float* __restrict__ w2, const float* __restrict__ b2, const float* __restrict__ g2,
    const float* __restrict__ be2, const float* __restrict__ m2, const float* __restrict__ v2,
    const float* __restrict__ w3, const float* __restrict__ b3, const float* __restrict__ g3,
    const float* __restrict__ be3, const float* __restrict__ m3, const float* __restrict__ v3,
    float* __restrict__ w1f, float* __restrict__ fb1,
    unsigned short* __restrict__ w2b, float* __restrict__ fb2,
    unsigned short* __restrict__ w3b, float* __restrict__ fb3)
{
    const int t  = blockIdx.x * 256 + threadIdx.x;
    const int nt = gridDim.x * 256;
    const float eps = 1e-5f;
    for (int i = t; i < 64 * 3; i += nt)    w1f[i] = w1[i] * (g1[i / 3] / sqrtf(v1[i / 3] + eps));
    for (int i = t; i < 64; i += nt)        fb1[i] = (b1[i] - m1[i]) * (g1[i] / sqrtf(v1[i] + eps)) + be1[i];
    for (int i = t; i < 128 * 64; i += nt)  w2b[i] = f2bf(w2[i] * (g2[i / 64] / sqrtf(v2[i / 64] + eps)));
    for (int i = t; i < 128; i += nt)       fb2[i] = (b2[i] - m2[i]) * (g2[i] / sqrtf(v2[i] + eps)) + be2[i];
    for (int i = t; i < 256 * 128; i += nt) w3b[i] = f2bf(w3[i] * (g3[i / 128] / sqrtf(v3[i / 128] + eps)));
    for (int i = t; i < 256; i += nt)       fb3[i] = (b3[i] - m3[i]) * (g3[i] / sqrtf(v3[i] + eps)) + be3[i];
}

// ---------------------------------------------------------------------------
// Kernel 1: chunked scan with wave-wide fast-skip. One wave per (seed, chunk).
// Semantics of top_k(-key): first <=64 passing indices ascending; (lane,j)
// lexicographic order = ascending point index. Fast-skip ballots the widest
// (level-3) mask; all-miss iterations skip the 4-level block (no semantic
// change: all level masks are subsets).
// ---------------------------------------------------------------------------
__global__ __launch_bounds__(256) void scan_kernel(
    const float* __restrict__ seedp, const float* __restrict__ pc,
    const float* __restrict__ rot, unsigned short* __restrict__ buf,
    int* __restrict__ cnts)
{
    const int lane = threadIdx.x & 63;
    const int W = blockIdx.x * 4 + (threadIdx.x >> 6);   // 0..16383
    const int g = W >> 3;
    const int c = W & 7;
    const int b = g >> 10;

    const float* sd = seedp + (size_t)g * 3;
    const float sx = sd[0], sy = sd[1], sz = sd[2];
    const float* R = rot + (size_t)g * 9;
    const float r00 = R[0], r01 = R[1], r02 = R[2];
    const float r10 = R[3], r11 = R[4], r12 = R[5];
    const float r20 = R[6], r21 = R[7], r22 = R[8];

    const float* pcb = pc + (size_t)b * NPT * 3;
    unsigned short* bufg = buf + (size_t)g * (NLVL * NCHUNK * 64);

    int cnt0 = 0, cnt1 = 0, cnt2 = 0, cnt3 = 0;
    const unsigned long long lm = (1ull << lane) - 1ull;
    const int base = c * CHSZ;

    for (int it = 0; it < CHSZ / 256; ++it) {
        const int p0 = base + it * 256 + lane * 4;
        const float4 q0 = *(const float4*)(pcb + (size_t)p0 * 3);
        const float4 q1 = *(const float4*)(pcb + (size_t)p0 * 3 + 4);
        const float4 q2 = *(const float4*)(pcb + (size_t)p0 * 3 + 8);

        float hh[4];
        bool  m3v[4];
        {
            const float px[4] = {q0.x, q0.w, q1.z, q2.y};
            const float py[4] = {q0.y, q1.x, q1.w, q2.z};
            const float pz[4] = {q0.z, q1.y, q2.x, q2.w};
            #pragma unroll
            for (int j = 0; j < 4; ++j) {
                const float dx = px[j] - sx, dy = py[j] - sy, dz = pz[j] - sz;
                const float h = dx * r00 + dy * r10 + dz * r20;
                const float u = dx * r01 + dy * r11 + dz * r21;
                const float v = dx * r02 + dy * r12 + dz * r22;
                const float r2 = u * u + v * v;
                hh[j] = h;
                m3v[j] = (r2 < 0.0025f) && (h > -0.02f) && (h < 0.04f);
            }
        }
        if (__ballot(m3v[0] || m3v[1] || m3v[2] || m3v[3]) == 0ull) continue;

        #pragma unroll
        for (int l = 0; l < NLVL; ++l) {
            const float hm = (l == 0) ? 0.01f : (l == 1) ? 0.02f : (l == 2) ? 0.03f : 0.04f;
            const bool m0 = m3v[0] && (hh[0] < hm);
            const bool m1 = m3v[1] && (hh[1] < hm);
            const bool m2 = m3v[2] && (hh[2] < hm);
            const bool m3 = m3v[3] && (hh[3] < hm);
            const unsigned long long b0 = __ballot(m0);
            const unsigned long long b1 = __ballot(m1);
            const unsigned long long b2 = __ballot(m2);
            const unsigned long long b3 = __ballot(m3);
            int& cnt = (l == 0) ? cnt0 : (l == 1) ? cnt1 : (l == 2) ? cnt2 : cnt3;
            const int lanePref = (int)(__popcll(b0 & lm) + __popcll(b1 & lm) +
                                       __popcll(b2 & lm) + __popcll(b3 & lm));
            unsigned short* ob = bufg + (l * NCHUNK + c) * 64;
            int own = 0;
            if (m0) { const int pos = cnt + lanePref;       if (pos < 64) ob[pos] = (unsigned short)(p0);     own = 1; }
            if (m1) { const int pos = cnt + lanePref + own; if (pos < 64) ob[pos] = (unsigned short)(p0 + 1); ++own; }
            if (m2) { const int pos = cnt + lanePref + own; if (pos < 64) ob[pos] = (unsigned short)(p0 + 2); ++own; }
            if (m3) { const int pos = cnt + lanePref + own; if (pos < 64) ob[pos] = (unsigned short)(p0 + 3); ++own; }
            cnt += (int)(__popcll(b0) + __popcll(b1) + __popcll(b2) + __popcll(b3));
        }
        if (cnt0 >= NSAMP) break;   // nested masks: level 0 fills last
    }

    if (lane == 0) {
        int* cg = cnts + (size_t)g * (NLVL * NCHUNK);
        cg[0 * NCHUNK + c] = cnt0;
        cg[1 * NCHUNK + c] = cnt1;
        cg[2 * NCHUNK + c] = cnt2;
        cg[3 * NCHUNK + c] = cnt3;
    }
}

// ---------------------------------------------------------------------------
// Kernel 2: fused merge + 3-layer MLP + max-pool. One block per (g,lvl).
//
// LDS: k-block-major bf16 layout  h[kblk][n][8]  (kblk = k/8, n = sample).
// B-fragment ds_read_b128: lane(quad,lane15) reads ((k0*4+quad)*64 + n)*16B
// -> lane15-consecutive 16B units, the canonical conflict-free pattern.
//   h1t: 8 kblk  (8 KB)      h2t: 16 kblk (16 KB)
//   xt (fp32 x[3][64], 768 B) overlays the h2t region (dead after layer 1).
// Layer 1 is FP32 VALU (accuracy-critical); layers 2/3 are bf16 MFMA
// (16x16x32, C/D: col=lane15, row=quad*4+reg). Layer-3 epilogue: in-register
// max over nt, DPP row_ror reduction over the 16 cols, bias post-max (exact:
// per-channel bias commutes with max), ReLU, store.
// ---------------------------------------------------------------------------
__global__ __launch_bounds__(256) void mlp_kernel(
    const float* __restrict__ seedp, const float* __restrict__ pc,
    const float* __restrict__ rot,
    const unsigned short* __restrict__ buf, const int* __restrict__ cnts,
    const float* __restrict__ w1f, const float* __restrict__ fb1,
    const unsigned short* __restrict__ w2b, const float* __restrict__ fb2,
    const unsigned short* __restrict__ w3b, const float* __restrict__ fb3,
    float* __restrict__ out)
{
    __shared__ unsigned short lds[12288];          // 24 KB
    unsigned short* h1t = lds;                     // [8][64][8]
    unsigned short* h2t = lds + 4096;              // [16][64][8]
    float* xt = (float*)(lds + 4096);              // [3][64] fp32, dead after L1

    const int gp = blockIdx.x;                     // 0..8191
    const int g = gp >> 2, l = gp & 3;
    const int b = g >> 10, s = g & 1023;
    const int tid = threadIdx.x;
    const int n      = tid & 63;
    const int w      = tid >> 6;
    const int lane15 = tid & 15;
    const int quad   = (tid & 63) >> 4;

    // ---- merge: wave 0 gathers the 64 selected points, rotates, fills xt fp32
    if (w == 0) {
        const int lane = tid;
        const int* cg = cnts + (size_t)g * (NLVL * NCHUNK) + l * NCHUNK;
        const unsigned short* bl = buf + (size_t)g * (NLVL * NCHUNK * 64) + l * (NCHUNK * 64);
        int idx = -1, acc = 0, firstIdx = -1;
        #pragma unroll
        for (int c = 0; c < NCHUNK; ++c) {
            const int cn = min(cg[c], 64);
            if (cn > 0 && firstIdx < 0) firstIdx = (int)bl[c * 64];
            if (lane >= acc && lane < acc + cn) idx = (int)bl[c * 64 + (lane - acc)];
            acc += cn;
        }
        if (idx < 0) idx = (firstIdx >= 0) ? firstIdx : 0;
        const float* sd = seedp + (size_t)g * 3;
        const float* R  = rot   + (size_t)g * 9;
        const float* pp = pc + ((size_t)b * NPT + idx) * 3;
        const float dx = pp[0] - sd[0], dy = pp[1] - sd[1], dz = pp[2] - sd[2];
        xt[lane]       = dx * R[0] + dy * R[3] + dz * R[6];
        xt[64 + lane]  = dx * R[1] + dy * R[4] + dz * R[7];
        xt[128 + lane] = dx * R[2] + dy * R[5] + dz * R[8];
    }
    __syncthreads();

    // ---- Layer 1: 3 -> 64, FP32 VALU; write h1t (bf16, kblk-major)
    {
        const float x0 = xt[n], x1 = xt[64 + n], x2 = xt[128 + n];
        unsigned int p[8];
        #pragma unroll
        for (int j = 0; j < 8; ++j) {
            const int o0 = __builtin_amdgcn_readfirstlane(w * 16 + 2 * j);
            const float a0 = fb1[o0]     + w1f[o0*3]*x0   + w1f[o0*3+1]*x1 + w1f[o0*3+2]*x2;
            const float a1 = fb1[o0 + 1] + w1f[o0*3+3]*x0 + w1f[o0*3+4]*x1 + w1f[o0*3+5]*x2;
            p[j] = f2bf2(fmaxf(a0, 0.f), fmaxf(a1, 0.f));
        }
        // channels w*16..w*16+15 = kblk w*2 (p0..p3) and w*2+1 (p4..p7)
        *(uintx4*)&h1t[(((w * 2)     ) * 64 + n) * 8] = (uintx4){p[0], p[1], p[2], p[3]};
        *(uintx4*)&h1t[(((w * 2) + 1 ) * 64 + n) * 8] = (uintx4){p[4], p[5], p[6], p[7]};
    }
    __syncthreads();

    // ---- Layer 2: 64 -> 128 (MFMA), write h2t kblk-major
    {
        short8 bfr[4][2];
        #pragma unroll
        for (int nt = 0; nt < 4; ++nt)
            #pragma unroll
            for (int k0 = 0; k0 < 2; ++k0)
                bfr[nt][k0] = *(const short8*)&h1t[((k0 * 4 + quad) * 64 + nt * 16 + lane15) * 8];

        #pragma unroll
        for (int mi = 0; mi < 2; ++mi) {
            const int m0 = (w * 2 + mi) * 16;
            const short8 a0 = *(const short8*)&w2b[(m0 + lane15) * 64 + quad * 8];
            const short8 a1 = *(const short8*)&w2b[(m0 + lane15) * 64 + 32 + quad * 8];
            const floatx4 bias = *(const floatx4*)&fb2[m0 + quad * 4];
            #pragma unroll
            for (int nt = 0; nt < 4; ++nt) {
                floatx4 acc = bias;
                acc = __builtin_amdgcn_mfma_f32_16x16x32_bf16(a0, bfr[nt][0], acc, 0, 0, 0);
                acc = __builtin_amdgcn_mfma_f32_16x16x32_bf16(a1, bfr[nt][1], acc, 0, 0, 0);
                const int n2 = nt * 16 + lane15;
                const unsigned int q0 = f2bf2(fmaxf(acc[0], 0.f), fmaxf(acc[1], 0.f));
                const unsigned int q1 = f2bf2(fmaxf(acc[2], 0.f), fmaxf(acc[3], 0.f));
                const int kb = (m0 >> 3) + (quad >> 1);   // channels m0+quad*4.. -> kblk, pos (quad&1)*4
                *(uintx2*)&h2t[(kb * 64 + n2) * 8 + (quad & 1) * 4] = (uintx2){q0, q1};
            }
        }
    }
    __syncthreads();

    // ---- Layer 3: 128 -> 256 (MFMA), fused bias/relu/max-pool
    {
        short8 bfr[4][4];
        #pragma unroll
        for (int nt = 0; nt < 4; ++nt)
            #pragma unroll
            for (int k0 = 0; k0 < 4; ++k0)
                bfr[nt][k0] = *(const short8*)&h2t[((k0 * 4 + quad) * 64 + nt * 16 + lane15) * 8];

        #pragma unroll
        for (int mt = 0; mt < 4; ++mt) {
            const int m0 = (w * 4 + mt) * 16;
            short8 a[4];
            #pragma unroll
            for (int k0 = 0; k0 < 4; ++k0)
                a[k0] = *(const short8*)&w3b[(m0 + lane15) * 128 + k0 * 32 + quad * 8];

            floatx4 acc[4];
            #pragma unroll
            for (int nt = 0; nt < 4; ++nt) acc[nt] = (floatx4){0.f, 0.f, 0.f, 0.f};
            #pragma unroll
            for (int k0 = 0; k0 < 4; ++k0)
                #pragma unroll
                for (int nt = 0; nt < 4; ++nt)
                    acc[nt] = __builtin_amdgcn_mfma_f32_16x16x32_bf16(a[k0], bfr[nt][k0], acc[nt], 0, 0, 0);

            const floatx4 bias = *(const floatx4*)&fb3[m0 + quad * 4];
            #pragma unroll
            for (int r = 0; r < 4; ++r) {
                float t = fmaxf(fmaxf(acc[0][r], acc[1][r]), fmaxf(acc[2][r], acc[3][r]));
                t = fmax_rot16(t);
                if (lane15 == 0) {
                    const int o = m0 + quad * 4 + r;
                    out[(((size_t)b * 256 + o) * 1024 + s) * 4 + l] = fmaxf(t + bias[r], 0.f);
                }
            }
        }
    }
}

// ---------------------------------------------------------------------------
// Workspace layout:
//   w1f fl[192]  fb1 fl[64]  fb2 fl[128]  fb3 fl[256]
//   w2b us[8192]  w3b us[32768]
//   buf us[2048*4*8*64 = 4,194,304]   cnts int[65,536]
// total ~8.7 MB
// ---------------------------------------------------------------------------
extern "C" void kernel_launch(void* const* d_in, const int* in_sizes, int n_in,
                              void* d_out, int out_size, void* d_ws, size_t ws_size,
                              hipStream_t stream) {
    const float* seed = (const float*)d_in[0];
    const float* pc   = (const float*)d_in[1];
    const float* rot  = (const float*)d_in[2];
    const float* w1 = (const float*)d_in[3];
    const float* b1 = (const float*)d_in[4];
    const float* g1 = (const float*)d_in[5];
    const float* be1 = (const float*)d_in[6];
    const float* m1 = (const float*)d_in[7];
    const float* v1 = (const float*)d_in[8];
    const float* w2 = (const float*)d_in[9];
    const float* b2 = (const float*)d_in[10];
    const float* g2 = (const float*)d_in[11];
    const float* be2 = (const float*)d_in[12];
    const float* m2 = (const float*)d_in[13];
    const float* v2 = (const float*)d_in[14];
    const float* w3 = (const float*)d_in[15];
    const float* b3 = (const float*)d_in[16];
    const float* g3 = (const float*)d_in[17];
    const float* be3 = (const float*)d_in[18];
    const float* m3 = (const float*)d_in[19];
    const float* v3 = (const float*)d_in[20];

    float* w1f = (float*)d_ws;                            // 192
    float* fb1 = w1f + 192;                               // 64
    float* fb2 = fb1 + 64;                                // 128
    float* fb3 = fb2 + 128;                               // 256
    unsigned short* w2b = (unsigned short*)(fb3 + 256);   // 8192
    unsigned short* w3b = w2b + 8192;                     // 32768
    unsigned short* buf = w3b + 32768;                    // 4,194,304
    int* cnts = (int*)(buf + 4194304);                    // 65,536

    prep_kernel<<<64, 256, 0, stream>>>(w1, b1, g1, be1, m1, v1,
                                        w2, b2, g2, be2, m2, v2,
                                        w3, b3, g3, be3, m3, v3,
                                        w1f, fb1, w2b, fb2, w3b, fb3);
    scan_kernel<<<4096, 256, 0, stream>>>(seed, pc, rot, buf, cnts);
    mlp_kernel<<<8192, 256, 0, stream>>>(seed, pc, rot, buf, cnts,
                                         w1f, fb1, w2b, fb2, w3b, fb3,
                                         (float*)d_out);
}